// Round 7
// baseline (449.024 us; speedup 1.0000x reference)
//
#include <hip/hip_runtime.h>
#include <hip/hip_bf16.h>

// Attention forward, MI355X (gfx950). fp32 in/out, bf16 MFMA internally.
// ws (56 MB): wqkv_b[3072x1024 bf16] | wo_b[1024x1024 bf16] | QKV[8192x3072 bf16]
// xb (bf16 x) lives in d_out's first 16 MB (dead before out-proj writes).
// Dispatches: 5 converts; QKV GEMM (bf16 m97-style); flash (fixed-shift
// softmax, Z in-place over Q cols); out-proj GEMM (fp32 out).
// MFMA layouts (verified m89/m74):
//   A-frag: A[m=lane&15][k=(lane>>4)*8+j]; B-frag: B[n=lane&15][k=...]
//   C/D:    col=lane&15, row=(lane>>4)*4+reg

typedef short short8 __attribute__((ext_vector_type(8)));
typedef float f32x4 __attribute__((ext_vector_type(4)));

#define MFMA16(a, b, c) __builtin_amdgcn_mfma_f32_16x16x32_bf16((a), (b), (c), 0, 0, 0)

static __device__ __forceinline__ ushort f2bf(float f) {
  union { __hip_bfloat16 h; ushort u; } cv;
  cv.h = __float2bfloat16(f);
  return cv.u;
}

static __device__ __forceinline__ float fexp2(float x) {
#if __has_builtin(__builtin_amdgcn_exp2f)
  return __builtin_amdgcn_exp2f(x);
#else
  return __expf(x * 0.69314718056f);
#endif
}

static __device__ __forceinline__ void store_out(float* p, float v) { *p = v; }
static __device__ __forceinline__ void store_out(__hip_bfloat16* p, float v) {
  *p = __float2bfloat16(v);
}

__global__ __launch_bounds__(256) void f32_to_bf16_kernel(
    const float* __restrict__ in, ushort* __restrict__ out, int n4) {
  int i = blockIdx.x * blockDim.x + threadIdx.x;
  if (i >= n4) return;
  const float4 v = ((const float4*)in)[i];
  ushort4 o;
  o.x = f2bf(v.x); o.y = f2bf(v.y); o.z = f2bf(v.z); o.w = f2bf(v.w);
  ((ushort4*)out)[i] = o;
}

// C[M,N] = A[M,K](bf16) * B[N,K]^T(bf16), fp32 acc. m97 structure: 128x128
// block tile, BK=32, both operands staged via global_load_lds width 16,
// ds_read_b128 fragments. Block 256 = 4 waves, wave tile 64x64.
template <typename OUT_T>
__global__ __launch_bounds__(256) void gemm_kernel(
    const ushort* __restrict__ A, int lda, const ushort* __restrict__ B, int ldb,
    OUT_T* __restrict__ C, int ldc, int K) {
  __shared__ __align__(16) ushort As[128 * 32];
  __shared__ __align__(16) ushort Bs[128 * 32];
  const int tid = threadIdx.x;
  const int wave = tid >> 6, lane = tid & 63;
  const int lm = lane & 15, quad = lane >> 4;
  const size_t m0 = (size_t)blockIdx.y * 128;
  const size_t n0 = (size_t)blockIdx.x * 128;
  const int srow = lane >> 2;       // 4 lanes/row * 8 ushort
  const int scol = (lane & 3) * 8;

  f32x4 acc[4][4] = {};
  for (int k0 = 0; k0 < K; k0 += 32) {
    __syncthreads();
#pragma unroll
    for (int j = 0; j < 2; ++j) {
      const int ch = wave * 2 + j;  // 16-row chunk
      const ushort* gb = B + (n0 + ch * 16 + srow) * (size_t)ldb + k0 + scol;
      __builtin_amdgcn_global_load_lds(
          (const __attribute__((address_space(1))) void*)gb,
          (__attribute__((address_space(3))) void*)(Bs + ch * 512), 16, 0, 0);
      const ushort* ga = A + (m0 + ch * 16 + srow) * (size_t)lda + k0 + scol;
      __builtin_amdgcn_global_load_lds(
          (const __attribute__((address_space(1))) void*)ga,
          (__attribute__((address_space(3))) void*)(As + ch * 512), 16, 0, 0);
    }
    __syncthreads();

    const int wm = (wave >> 1) * 64, wn = (wave & 1) * 64;
    short8 a[4], b[4];
#pragma unroll
    for (int i = 0; i < 4; ++i)
      a[i] = *(const short8*)(As + (wm + i * 16 + lm) * 32 + quad * 8);
#pragma unroll
    for (int j = 0; j < 4; ++j)
      b[j] = *(const short8*)(Bs + (wn + j * 16 + lm) * 32 + quad * 8);
#pragma unroll
    for (int i = 0; i < 4; ++i)
#pragma unroll
      for (int j = 0; j < 4; ++j)
        acc[i][j] = MFMA16(a[i], b[j], acc[i][j]);
  }

  const int wm = (wave >> 1) * 64, wn = (wave & 1) * 64;
  const int rq = quad * 4;
#pragma unroll
  for (int i = 0; i < 4; ++i)
#pragma unroll
    for (int j = 0; j < 4; ++j)
#pragma unroll
      for (int r = 0; r < 4; ++r)
        store_out(&C[(m0 + wm + i * 16 + rq + r) * (size_t)ldc + n0 + wn + j * 16 + lm],
                  acc[i][j][r]);
}

// Flash causal attention. QKV[8192][3072]: Q cols 0..1023, K 1024..2047,
// V 2048..3071; head h at sub-col h*64; row = b*2048 + pos. Z over Q in-place.
// Grid (32,16,4), one 64-q tile per block, longest-first (qbi = 31-bx).
// Block = 4 waves; wave = 16 q-rows. S^T = K*Q^T: lane owns q-row qrow+lm.
// Fixed-shift softmax: p = exp2(S*log2e/8) (exact; scores bounded ~10),
// l accumulated per-lane, reduced once in epilogue. K prefetched to regs;
// V^T double-buffered in LDS (xor-swizzled); P via per-wave LDS (no barrier).
// PS=72: P^T rows are 64 wide (s*16+quad*4+rp*2+1 in [0,64)) + 8 pad.
__global__ __launch_bounds__(256) void flash3_kernel(ushort* __restrict__ QKV) {
  constexpr int LD = 3072;
  constexpr int PS = 72;
  __shared__ __align__(16) ushort vt[2][64 * 64];
  __shared__ __align__(16) ushort pbuf[4][16 * PS];

  const int qbi = 31 - (int)blockIdx.x;  // long blocks dispatch first (LPT)
  const int head = blockIdx.y;
  const int b = blockIdx.z;
  const int tid = threadIdx.x;
  const int wave = tid >> 6, lane = tid & 63;
  const int lm = lane & 15, quad = lane >> 4;

  const size_t qcol = (size_t)b * 2048 * LD + head * 64;
  const size_t kcol = qcol + 1024;
  const size_t vcol = qcol + 2048;
  const int qb = qbi * 64;
  const int qrow = qb + wave * 16;
  const int qg = qrow + lm;
  const int nt = qbi + 1;

  const int h0 = (tid & 7) * 8;  // staging: 8 V-cols per thread
  const int hsw = tid & 7;       // == h>>3 for those cols
  const int plb = tid >> 3;      // staging p base (0..31)

  short8 qa0 = *(const short8*)(QKV + qcol + (size_t)(qrow + lm) * LD + quad * 8);
  short8 qa1 = *(const short8*)(QKV + qcol + (size_t)(qrow + lm) * LD + 32 + quad * 8);

  f32x4 accz[4] = {};   // Z C-layout: row q=quad*4+r, col h=c*16+lm
  float l_l = 0.f;      // per-lane partial row-sum for row qg

  // K fragments for tile 0 (registers)
  short8 ka[4], kb[4];
#pragma unroll
  for (int s = 0; s < 4; ++s) {
    const ushort* kp = QKV + kcol + (size_t)(s * 16 + lm) * LD;
    ka[s] = *(const short8*)(kp + quad * 8);
    kb[s] = *(const short8*)(kp + 32 + quad * 8);
  }
  // V tile 0: load + swizzled LDS write (before first barrier)
  {
#pragma unroll
    for (int rr = 0; rr < 2; ++rr) {
      const int p = plb + rr * 32;
      short8 v = *(const short8*)(QKV + vcol + (size_t)p * LD + h0);
      ushort* dst = &vt[0][h0 * 64 + ((((p >> 3) ^ hsw) & 7) << 3) + (p & 7)];
#pragma unroll
      for (int u = 0; u < 8; ++u) dst[u * 64] = ((const ushort*)&v)[u];
    }
  }

  constexpr float CSC = 0.180336880f;  // log2(e)/8

  for (int it = 0; it < nt; ++it) {
    const int p0 = it * 64;
    __syncthreads();  // vt[it&1] visible; prior reads of other buf done

    // early global V load for it+1 (LDS write deferred to end of iter)
    short8 nv0, nv1;
    if (it + 1 < nt) {
      nv0 = *(const short8*)(QKV + vcol + (size_t)(p0 + 64 + plb) * LD + h0);
      nv1 = *(const short8*)(QKV + vcol + (size_t)(p0 + 96 + plb) * LD + h0);
    }

    // scores S^T[p][q] (8 MFMA), consuming prefetched K
    f32x4 t4[4];
#pragma unroll
    for (int s = 0; s < 4; ++s) {
      f32x4 t = {0.f, 0.f, 0.f, 0.f};
      t = MFMA16(ka[s], qa0, t);
      t = MFMA16(kb[s], qa1, t);
      t4[s] = t;
    }
    // reload K for it+1 (WAR on the MFMAs above; loads fly during this iter)
    if (it + 1 < nt) {
#pragma unroll
      for (int s = 0; s < 4; ++s) {
        const ushort* kp = QKV + kcol + (size_t)(p0 + 64 + s * 16 + lm) * LD;
        ka[s] = *(const short8*)(kp + quad * 8);
        kb[s] = *(const short8*)(kp + 32 + quad * 8);
      }
    }

    // fixed-shift softmax: p = exp2(S*log2e/8); mask only on diagonal tile
    float ps[4][4];
    if (it != nt - 1) {
#pragma unroll
      for (int s = 0; s < 4; ++s)
#pragma unroll
        for (int r = 0; r < 4; ++r) {
          ps[s][r] = fexp2(t4[s][r] * CSC);
          l_l += ps[s][r];
        }
    } else {
#pragma unroll
      for (int s = 0; s < 4; ++s)
#pragma unroll
        for (int r = 0; r < 4; ++r) {
          const int pg = p0 + s * 16 + quad * 4 + r;
          const float e = fexp2(t4[s][r] * CSC);
          ps[s][r] = (pg > qg) ? 0.f : e;
          l_l += ps[s][r];
        }
    }

    // pack P^T (C-layout) -> per-wave LDS (same-wave, no barrier)
    ushort* pw = pbuf[wave] + lm * PS;
#pragma unroll
    for (int s = 0; s < 4; ++s)
#pragma unroll
      for (int rp = 0; rp < 2; ++rp) {
        const uint pk = (uint)f2bf(ps[s][rp * 2]) |
                        ((uint)f2bf(ps[s][rp * 2 + 1]) << 16);
        *(uint*)(pw + s * 16 + quad * 4 + rp * 2) = pk;
      }

    // PV: accz[q][h] += P[q][p] * V[p][h]
#pragma unroll
    for (int kc = 0; kc < 2; ++kc) {
      short8 pa = *(const short8*)(pw + kc * 32 + quad * 8);
#pragma unroll
      for (int c = 0; c < 4; ++c) {
        const int hrow = c * 16 + lm;
        short8 vb = *(const short8*)(
            &vt[it & 1][hrow * 64 + (((4 * kc + quad) ^ (hrow >> 3)) << 3)]);
        accz[c] = MFMA16(pa, vb, accz[c]);
      }
    }

    // late LDS writes of next V tile (other buffer)
    if (it + 1 < nt) {
      {
        const int p = plb;
        ushort* dst = &vt[(it + 1) & 1][h0 * 64 + ((((p >> 3) ^ hsw) & 7) << 3) + (p & 7)];
#pragma unroll
        for (int u = 0; u < 8; ++u) dst[u * 64] = ((const ushort*)&nv0)[u];
      }
      {
        const int p = plb + 32;
        ushort* dst = &vt[(it + 1) & 1][h0 * 64 + ((((p >> 3) ^ hsw) & 7) << 3) + (p & 7)];
#pragma unroll
        for (int u = 0; u < 8; ++u) dst[u * 64] = ((const ushort*)&nv1)[u];
      }
    }
  }

  // epilogue: full row-sums via 2 shfl_xor, then scale + write Z over Q
  float lt = l_l;
  lt += __shfl_xor(lt, 16, 64);
  lt += __shfl_xor(lt, 32, 64);
#pragma unroll
  for (int r = 0; r < 4; ++r) {
    const float lr = __shfl(lt, quad * 4 + r, 64);
    const float inv = 1.f / lr;
#pragma unroll
    for (int c = 0; c < 4; ++c)
      QKV[qcol + (size_t)(qrow + quad * 4 + r) * LD + c * 16 + lm] =
          f2bf(accz[c][r] * inv);
  }
}

extern "C" void kernel_launch(void* const* d_in, const int* in_sizes, int n_in,
                              void* d_out, int out_size, void* d_ws, size_t ws_size,
                              hipStream_t stream) {
  (void)in_sizes; (void)n_in; (void)out_size; (void)ws_size;
  const float* x  = (const float*)d_in[0];   // (4,2048,1024) = (8192,1024)
  const float* wk = (const float*)d_in[1];   // (16,64,1024) flat (1024,1024)
  const float* wq = (const float*)d_in[2];
  const float* wv = (const float*)d_in[3];
  const float* wo = (const float*)d_in[4];   // (1024,1024)
  float* out = (float*)d_out;

  const size_t WSZ = (size_t)1024 * 1024;
  ushort* wqkv_b = (ushort*)d_ws;            // rows: 0..1023 Q, 1024.. K, 2048.. V
  ushort* wo_b = wqkv_b + 3 * WSZ;
  ushort* QKV = wo_b + WSZ;                  // 8192 x 3072
  ushort* xb = (ushort*)d_out;               // bf16 x in d_out (16 of 32 MB);
                                             // dead before out-proj writes

  const int wn4 = (int)(WSZ / 4);
  const int xn4 = (int)((size_t)8192 * 1024 / 4);
  f32_to_bf16_kernel<<<(wn4 + 255) / 256, 256, 0, stream>>>(wq, wqkv_b, wn4);
  f32_to_bf16_kernel<<<(wn4 + 255) / 256, 256, 0, stream>>>(wk, wqkv_b + WSZ, wn4);
  f32_to_bf16_kernel<<<(wn4 + 255) / 256, 256, 0, stream>>>(wv, wqkv_b + 2 * WSZ, wn4);
  f32_to_bf16_kernel<<<(wn4 + 255) / 256, 256, 0, stream>>>(wo, wo_b, wn4);
  f32_to_bf16_kernel<<<(xn4 + 255) / 256, 256, 0, stream>>>(x, xb, xn4);

  // All-batch QKV projection (pure bf16, global_load_lds staging).
  gemm_kernel<__hip_bfloat16><<<dim3(24, 64), 256, 0, stream>>>(
      xb, 1024, wqkv_b, 1024, (__hip_bfloat16*)QKV, 3072, 1024);

  flash3_kernel<<<dim3(32, 16, 4), 256, 0, stream>>>(QKV);

  // Out projection: Z (QKV cols 0..1023) * Wo^T -> fp32 out.
  gemm_kernel<float><<<dim3(8, 64), 256, 0, stream>>>(
      QKV, 3072, wo_b, 1024, out, 1024, 1024);
}

// Round 11
// 355.592 us; speedup vs baseline: 1.2628x; 1.2628x over previous
//
#include <hip/hip_runtime.h>
#include <hip/hip_bf16.h>

// Attention forward, MI355X (gfx950). fp32 in/out, bf16 MFMA internally.
// ws (56 MB): wqkv_b[3072x1024 bf16] | wo_b[1024x1024 bf16] | QKV[8192x3072 bf16]
// xb (bf16 x) lives in d_out's first 16 MB (dead before out-proj writes).
// Dispatches: 5 converts; QKV GEMM (bf16 m97-style); flash (paired q-tiles,
// fixed-shift softmax, Z in-place over Q cols); out-proj GEMM (fp32 out).
// MFMA layouts (verified m89/m74):
//   A-frag: A[m=lane&15][k=(lane>>4)*8+j]; B-frag: B[n=lane&15][k=...]
//   C/D:    col=lane&15, row=(lane>>4)*4+reg

typedef short short8 __attribute__((ext_vector_type(8)));
typedef float f32x4 __attribute__((ext_vector_type(4)));

#define MFMA16(a, b, c) __builtin_amdgcn_mfma_f32_16x16x32_bf16((a), (b), (c), 0, 0, 0)

static __device__ __forceinline__ ushort f2bf(float f) {
  union { __hip_bfloat16 h; ushort u; } cv;
  cv.h = __float2bfloat16(f);
  return cv.u;
}

static __device__ __forceinline__ float fexp2(float x) {
#if __has_builtin(__builtin_amdgcn_exp2f)
  return __builtin_amdgcn_exp2f(x);
#else
  return __expf(x * 0.69314718056f);
#endif
}

static __device__ __forceinline__ void store_out(float* p, float v) { *p = v; }
static __device__ __forceinline__ void store_out(__hip_bfloat16* p, float v) {
  *p = __float2bfloat16(v);
}

__global__ __launch_bounds__(256) void f32_to_bf16_kernel(
    const float* __restrict__ in, ushort* __restrict__ out, int n4) {
  int i = blockIdx.x * blockDim.x + threadIdx.x;
  if (i >= n4) return;
  const float4 v = ((const float4*)in)[i];
  ushort4 o;
  o.x = f2bf(v.x); o.y = f2bf(v.y); o.z = f2bf(v.z); o.w = f2bf(v.w);
  ((ushort4*)out)[i] = o;
}

// C[M,N] = A[M,K](bf16) * B[N,K]^T(bf16), fp32 acc. m97 structure: 128x128
// block tile, BK=32, both operands staged via global_load_lds width 16,
// ds_read_b128 fragments. Block 256 = 4 waves, wave tile 64x64.
template <typename OUT_T>
__global__ __launch_bounds__(256) void gemm_kernel(
    const ushort* __restrict__ A, int lda, const ushort* __restrict__ B, int ldb,
    OUT_T* __restrict__ C, int ldc, int K) {
  __shared__ __align__(16) ushort As[128 * 32];
  __shared__ __align__(16) ushort Bs[128 * 32];
  const int tid = threadIdx.x;
  const int wave = tid >> 6, lane = tid & 63;
  const int lm = lane & 15, quad = lane >> 4;
  const size_t m0 = (size_t)blockIdx.y * 128;
  const size_t n0 = (size_t)blockIdx.x * 128;
  const int srow = lane >> 2;       // 4 lanes/row * 8 ushort
  const int scol = (lane & 3) * 8;

  f32x4 acc[4][4] = {};
  for (int k0 = 0; k0 < K; k0 += 32) {
    __syncthreads();
#pragma unroll
    for (int j = 0; j < 2; ++j) {
      const int ch = wave * 2 + j;  // 16-row chunk
      const ushort* gb = B + (n0 + ch * 16 + srow) * (size_t)ldb + k0 + scol;
      __builtin_amdgcn_global_load_lds(
          (const __attribute__((address_space(1))) void*)gb,
          (__attribute__((address_space(3))) void*)(Bs + ch * 512), 16, 0, 0);
      const ushort* ga = A + (m0 + ch * 16 + srow) * (size_t)lda + k0 + scol;
      __builtin_amdgcn_global_load_lds(
          (const __attribute__((address_space(1))) void*)ga,
          (__attribute__((address_space(3))) void*)(As + ch * 512), 16, 0, 0);
    }
    __syncthreads();

    const int wm = (wave >> 1) * 64, wn = (wave & 1) * 64;
    short8 a[4], b[4];
#pragma unroll
    for (int i = 0; i < 4; ++i)
      a[i] = *(const short8*)(As + (wm + i * 16 + lm) * 32 + quad * 8);
#pragma unroll
    for (int j = 0; j < 4; ++j)
      b[j] = *(const short8*)(Bs + (wn + j * 16 + lm) * 32 + quad * 8);
#pragma unroll
    for (int i = 0; i < 4; ++i)
#pragma unroll
      for (int j = 0; j < 4; ++j)
        acc[i][j] = MFMA16(a[i], b[j], acc[i][j]);
  }

  const int wm = (wave >> 1) * 64, wn = (wave & 1) * 64;
  const int rq = quad * 4;
#pragma unroll
  for (int i = 0; i < 4; ++i)
#pragma unroll
    for (int j = 0; j < 4; ++j)
#pragma unroll
      for (int r = 0; r < 4; ++r)
        store_out(&C[(m0 + wm + i * 16 + rq + r) * (size_t)ldc + n0 + wn + j * 16 + lm],
                  acc[i][j][r]);
}

// Swizzled V^T LDS write: 8 cols starting at h0 for row p.
static __device__ __forceinline__ void vt_write8(ushort* vtbuf, int h0, int hsw,
                                                 int p, const short8& v) {
  ushort* dst = vtbuf + h0 * 64 + ((((p >> 3) ^ hsw) & 7) << 3) + (p & 7);
#pragma unroll
  for (int u = 0; u < 8; ++u) dst[u * 64] = ((const ushort*)&v)[u];
}

// Flash causal attention. QKV[8192][3072]: Q cols 0..1023, K 1024..2047,
// V 2048..3071; head h at sub-col h*64; row = b*2048 + pos. Z over Q in-place.
// Grid (16,16,4): block handles q-tile pair (bx, 31-bx) -> exactly 33 p-tile
// iters per block (balance by construction, immune to dispatch mapping;
// round-7 lesson: 32|256 makes same-CU blocks share qbi, LPT fails).
// Block = 4 waves; wave = 16 q-rows. S^T = K*Q^T: lane owns q-row qrow+lm.
// Fixed-shift softmax: p = exp2(S*log2e/8) (exact; scores bounded ~10),
// l accumulated per-lane, reduced once in epilogue. K prefetched to regs;
// V^T double-buffered in LDS (xor-swizzled); P via per-wave LDS (no barrier).
// PS=72: P^T rows are 64 wide + 8 pad.
__global__ __launch_bounds__(256) void flash4_kernel(ushort* __restrict__ QKV) {
  constexpr int LD = 3072;
  constexpr int PS = 72;
  __shared__ __align__(16) ushort vt[2][64 * 64];
  __shared__ __align__(16) ushort pbuf[4][16 * PS];

  const int head = blockIdx.y;
  const int b = blockIdx.z;
  const int tid = threadIdx.x;
  const int wave = tid >> 6, lane = tid & 63;
  const int lm = lane & 15, quad = lane >> 4;

  const size_t qcol = (size_t)b * 2048 * LD + head * 64;
  const size_t kcol = qcol + 1024;
  const size_t vcol = qcol + 2048;

  const int h0 = (tid & 7) * 8;  // staging: 8 V-cols per thread
  const int hsw = tid & 7;       // == h>>3 for those cols
  const int plb = tid >> 3;      // staging p base (0..31)

  constexpr float CSC = 0.180336880f;  // log2(e)/8

  for (int pass = 0; pass < 2; ++pass) {
    const int qbi = pass ? 31 - (int)blockIdx.x : (int)blockIdx.x;
    const int qb = qbi * 64;
    const int qrow = qb + wave * 16;
    const int qg = qrow + lm;
    const int nt = qbi + 1;

    const ushort* qp = QKV + qcol + (size_t)(qrow + lm) * LD;
    short8 qa0 = *(const short8*)(qp + quad * 8);
    short8 qa1 = *(const short8*)(qp + 32 + quad * 8);

    f32x4 accz[4] = {};   // Z C-layout: row q=quad*4+r, col h=c*16+lm
    float l_l = 0.f;      // per-lane partial row-sum for row qg

    // K fragments for tile 0 (registers)
    short8 ka[4], kb[4];
#pragma unroll
    for (int s = 0; s < 4; ++s) {
      const ushort* kp = QKV + kcol + (size_t)(s * 16 + lm) * LD;
      ka[s] = *(const short8*)(kp + quad * 8);
      kb[s] = *(const short8*)(kp + 32 + quad * 8);
    }

    __syncthreads();  // prior pass's vt reads complete before restage
    // V tile 0 -> vt[0]
#pragma unroll
    for (int rr = 0; rr < 2; ++rr) {
      const int p = plb + rr * 32;
      short8 v = *(const short8*)(QKV + vcol + (size_t)p * LD + h0);
      vt_write8(vt[0], h0, hsw, p, v);
    }

    for (int it = 0; it < nt; ++it) {
      const int p0 = it * 64;
      __syncthreads();  // vt[it&1] visible; prior reads of other buf done

      // early global V load for it+1 (LDS write deferred to end of iter)
      short8 nv0, nv1;
      const bool more = (it + 1 < nt);
      if (more) {
        nv0 = *(const short8*)(QKV + vcol + (size_t)(p0 + 64 + plb) * LD + h0);
        nv1 = *(const short8*)(QKV + vcol + (size_t)(p0 + 96 + plb) * LD + h0);
      }

      // scores S^T[p][q] (8 MFMA), consuming prefetched K
      f32x4 t4[4];
#pragma unroll
      for (int s = 0; s < 4; ++s) {
        f32x4 t = {0.f, 0.f, 0.f, 0.f};
        t = MFMA16(ka[s], qa0, t);
        t = MFMA16(kb[s], qa1, t);
        t4[s] = t;
      }
      // reload K for it+1 (loads fly during this iter's tail)
      if (more) {
#pragma unroll
        for (int s = 0; s < 4; ++s) {
          const ushort* kp = QKV + kcol + (size_t)(p0 + 64 + s * 16 + lm) * LD;
          ka[s] = *(const short8*)(kp + quad * 8);
          kb[s] = *(const short8*)(kp + 32 + quad * 8);
        }
      }

      // fixed-shift softmax: p = exp2(S*log2e/8); mask only on diagonal tile
      float ps[4][4];
      if (it != nt - 1) {
#pragma unroll
        for (int s = 0; s < 4; ++s)
#pragma unroll
          for (int r = 0; r < 4; ++r) {
            ps[s][r] = fexp2(t4[s][r] * CSC);
            l_l += ps[s][r];
          }
      } else {
#pragma unroll
        for (int s = 0; s < 4; ++s)
#pragma unroll
          for (int r = 0; r < 4; ++r) {
            const int pg = p0 + s * 16 + quad * 4 + r;
            const float e = fexp2(t4[s][r] * CSC);
            ps[s][r] = (pg > qg) ? 0.f : e;
            l_l += ps[s][r];
          }
      }

      // pack P^T (C-layout) -> per-wave LDS (same-wave, no barrier)
      ushort* pw = pbuf[wave] + lm * PS;
#pragma unroll
      for (int s = 0; s < 4; ++s)
#pragma unroll
        for (int rp = 0; rp < 2; ++rp) {
          const uint pk = (uint)f2bf(ps[s][rp * 2]) |
                          ((uint)f2bf(ps[s][rp * 2 + 1]) << 16);
          *(uint*)(pw + s * 16 + quad * 4 + rp * 2) = pk;
        }

      // PV: accz[q][h] += P[q][p] * V[p][h]
      const ushort* vbuf = vt[it & 1];
#pragma unroll
      for (int kc = 0; kc < 2; ++kc) {
        short8 pa = *(const short8*)(pw + kc * 32 + quad * 8);
#pragma unroll
        for (int c = 0; c < 4; ++c) {
          const int hrow = c * 16 + lm;
          short8 vb = *(const short8*)(
              vbuf + hrow * 64 + (((4 * kc + quad) ^ (hrow >> 3)) << 3));
          accz[c] = MFMA16(pa, vb, accz[c]);
        }
      }

      // late LDS writes of next V tile (other buffer)
      if (more) {
        ushort* nbuf = vt[(it + 1) & 1];
        vt_write8(nbuf, h0, hsw, plb, nv0);
        vt_write8(nbuf, h0, hsw, plb + 32, nv1);
      }
    }

    // epilogue: full row-sums via 2 shfl_xor, then scale + write Z over Q
    float lt = l_l;
    lt += __shfl_xor(lt, 16, 64);
    lt += __shfl_xor(lt, 32, 64);
#pragma unroll
    for (int r = 0; r < 4; ++r) {
      const float lr = __shfl(lt, quad * 4 + r, 64);
      const float inv = 1.f / lr;
#pragma unroll
      for (int c = 0; c < 4; ++c)
        QKV[qcol + (size_t)(qrow + quad * 4 + r) * LD + c * 16 + lm] =
            f2bf(accz[c][r] * inv);
    }
  }
}

extern "C" void kernel_launch(void* const* d_in, const int* in_sizes, int n_in,
                              void* d_out, int out_size, void* d_ws, size_t ws_size,
                              hipStream_t stream) {
  (void)in_sizes; (void)n_in; (void)out_size; (void)ws_size;
  const float* x  = (const float*)d_in[0];   // (4,2048,1024) = (8192,1024)
  const float* wk = (const float*)d_in[1];   // (16,64,1024) flat (1024,1024)
  const float* wq = (const float*)d_in[2];
  const float* wv = (const float*)d_in[3];
  const float* wo = (const float*)d_in[4];   // (1024,1024)
  float* out = (float*)d_out;

  const size_t WSZ = (size_t)1024 * 1024;
  ushort* wqkv_b = (ushort*)d_ws;            // rows: 0..1023 Q, 1024.. K, 2048.. V
  ushort* wo_b = wqkv_b + 3 * WSZ;
  ushort* QKV = wo_b + WSZ;                  // 8192 x 3072
  ushort* xb = (ushort*)d_out;               // bf16 x in d_out (16 of 32 MB);
                                             // dead before out-proj writes

  const int wn4 = (int)(WSZ / 4);
  const int xn4 = (int)((size_t)8192 * 1024 / 4);
  f32_to_bf16_kernel<<<(wn4 + 255) / 256, 256, 0, stream>>>(wq, wqkv_b, wn4);
  f32_to_bf16_kernel<<<(wn4 + 255) / 256, 256, 0, stream>>>(wk, wqkv_b + WSZ, wn4);
  f32_to_bf16_kernel<<<(wn4 + 255) / 256, 256, 0, stream>>>(wv, wqkv_b + 2 * WSZ, wn4);
  f32_to_bf16_kernel<<<(wn4 + 255) / 256, 256, 0, stream>>>(wo, wo_b, wn4);
  f32_to_bf16_kernel<<<(xn4 + 255) / 256, 256, 0, stream>>>(x, xb, xn4);

  // All-batch QKV projection (pure bf16, global_load_lds staging).
  gemm_kernel<__hip_bfloat16><<<dim3(24, 64), 256, 0, stream>>>(
      xb, 1024, wqkv_b, 1024, (__hip_bfloat16*)QKV, 3072, 1024);

  flash4_kernel<<<dim3(16, 16, 4), 256, 0, stream>>>(QKV);

  // Out projection: Z (QKV cols 0..1023) * Wo^T -> fp32 out.
  gemm_kernel<float><<<dim3(8, 64), 256, 0, stream>>>(
      QKV, 3072, wo_b, 1024, out, 1024, 1024);
}